// Round 1
// baseline (794.882 us; speedup 1.0000x reference)
//
#include <hip/hip_runtime.h>
#include <hip/hip_bf16.h>
#include <cstdint>

#define B_N 65536
#define F_N 64
#define L_N 32
#define E_N 512
// K = F*L = 2048, k-octs = 256

typedef short bf16x8 __attribute__((ext_vector_type(8)));
typedef float f32x4 __attribute__((ext_vector_type(4)));

typedef __attribute__((address_space(1))) const unsigned int gas_u32;
typedef __attribute__((address_space(3))) unsigned int las_u32;

__device__ __forceinline__ void gl2lds16(const void* g, void* l) {
  // async global->LDS, 16B/lane, LDS dest = wave-uniform base + lane*16
  __builtin_amdgcn_global_load_lds((gas_u32*)g, (las_u32*)l, 16, 0, 0);
}

// exact GELU via Abramowitz-Stegun 7.1.26 erf (|abs err| <= 1.5e-7)
__device__ __forceinline__ float gelu_exact(float v) {
  float z  = v * 0.7071067811865476f;
  float az = fabsf(z);
  float t  = __builtin_amdgcn_rcpf(fmaf(0.3275911f, az, 1.0f));
  float p  = t * fmaf(t, fmaf(t, fmaf(t, fmaf(t, 1.061405429f, -1.453152027f),
                                      1.421413741f), -0.284496736f), 0.254829592f);
  float e    = __expf(-z * z);
  float erfa = fmaf(-p, e, 1.0f);
  float er   = (z < 0.0f) ? -erfa : erfa;
  return v * fmaf(0.5f, er, 0.5f);
}

// ---------------- prep: softmax(w_raw), wb2 = w @ b2, w -> d_out tail ------
__global__ __launch_bounds__(256) void k_prep(const float* __restrict__ w_raw,
                                              const float* __restrict__ b2,
                                              float* __restrict__ w_s,
                                              float* __restrict__ wb2,
                                              float* __restrict__ out_tail) {
  __shared__ float sw[F_N];
  int tid = threadIdx.x;
  if (tid < F_N) {
    float m = -1e30f;
    for (int i = 0; i < F_N; i++) m = fmaxf(m, w_raw[i]);
    float s = 0.f;
    for (int i = 0; i < F_N; i++) s += expf(w_raw[i] - m);
    float wv = expf(w_raw[tid] - m) / s;
    sw[tid] = wv;
    w_s[tid] = wv;
    out_tail[tid] = wv;
  }
  __syncthreads();
  for (int e = tid; e < E_N; e += 256) {
    float a = 0.f;
    for (int f = 0; f < F_N; f++) a = fmaf(sw[f], b2[f * E_N + e], a);
    wb2[e] = a;
  }
}

// ---------------- W2 [2048][512] fp32 -> blocked bf16 [k_oct][e][8] --------
__global__ __launch_bounds__(256) void k_w2t(const float* __restrict__ W2,
                                             uint4* __restrict__ W2T) {
  __shared__ float ls[64 * 65];
  int kt = blockIdx.x >> 3, et = blockIdx.x & 7;
  int k0 = kt * 64, e0 = et * 64;
  int tid = threadIdx.x;
#pragma unroll
  for (int i = 0; i < 16; i++) {
    int idx = i * 256 + tid;
    int r = idx >> 6, c = idx & 63;
    ls[r * 65 + c] = W2[(size_t)(k0 + r) * E_N + e0 + c];
  }
  __syncthreads();
#pragma unroll
  for (int i = 0; i < 2; i++) {
    int t = i * 256 + tid;
    int ko = t >> 6, e = t & 63;
    union { __hip_bfloat162 p[4]; uint4 u; } pk;
#pragma unroll
    for (int d = 0; d < 4; d++)
      pk.p[d] = __float22bfloat162_rn(make_float2(ls[(ko * 8 + 2 * d) * 65 + e],
                                                  ls[(ko * 8 + 2 * d + 1) * 65 + e]));
    W2T[(size_t)(kt * 8 + ko) * E_N + e0 + e] = pk.u;
  }
}

// ---------------- Hw = w[f]*gelu(LN(enc@W1+b1)) bf16 blocked [k_oct][b][8] -
__global__ __launch_bounds__(256) void k_hw(const float* __restrict__ bf,
                                            const float* __restrict__ W1,
                                            const float* __restrict__ b1,
                                            const float* __restrict__ gamma,
                                            const float* __restrict__ beta,
                                            const float* __restrict__ w_s,
                                            uint4* __restrict__ Hw) {
  __shared__ float xs[64 * 65];
  int tid = threadIdx.x;
  int b0 = blockIdx.x * 64;
  // stage x tile [64 b][64 f] coalesced
#pragma unroll
  for (int i = 0; i < 16; i++) {
    int idx = i * 256 + tid;
    xs[(idx >> 6) * 65 + (idx & 63)] = bf[(size_t)b0 * F_N + idx];
  }
  __syncthreads();
  int wave = tid >> 6, lane = tid & 63;
  int b = b0 + lane;
  for (int it = 0; it < 16; ++it) {
    int f = __builtin_amdgcn_readfirstlane(it * 4 + wave);  // wave-uniform
    const float* w1f = W1 + f * (L_N * L_N);
    const float* b1f = b1 + f * L_N;
    const float* gf  = gamma + f * L_N;
    const float* bef = beta + f * L_N;
    float x = xs[lane * 65 + f];
    float h[32];
#pragma unroll
    for (int j = 0; j < 32; j++) h[j] = b1f[j];
    // t_i = x * 0.1*2^i / (2*pi)  (revolutions); exact doubling each iter
    float t = x * 0.015915494309189535f;
#pragma unroll
    for (int i = 0; i < 16; i++) {
      float y  = t - floorf(t);
      float sv = __builtin_amdgcn_sinf(y);   // sin(2*pi*y)
      float cv = __builtin_amdgcn_cosf(y);
      t = t + t;
#pragma unroll
      for (int j = 0; j < 32; j++) h[j] = fmaf(sv, w1f[i * 32 + j], h[j]);
#pragma unroll
      for (int j = 0; j < 32; j++) h[j] = fmaf(cv, w1f[512 + i * 32 + j], h[j]);
    }
    // LayerNorm over 32 (population var), gamma/beta, GELU, * w[f]
    float mu = 0.f;
#pragma unroll
    for (int j = 0; j < 32; j++) mu += h[j];
    mu *= (1.0f / 32.0f);
    float var = 0.f;
#pragma unroll
    for (int j = 0; j < 32; j++) { h[j] -= mu; var = fmaf(h[j], h[j], var); }
    float rs = __builtin_amdgcn_rsqf(fmaf(var, (1.0f / 32.0f), 1e-5f));
    float wf = w_s[f];
#pragma unroll
    for (int j = 0; j < 32; j++) {
      float hn = fmaf(h[j] * rs, gf[j], bef[j]);
      h[j] = gelu_exact(hn) * wf;
    }
    // store: 4 x 16B, wave covers 1KB contiguous per store (coalesced)
#pragma unroll
    for (int q = 0; q < 4; q++) {
      union { __hip_bfloat162 p[4]; uint4 u; } pk;
#pragma unroll
      for (int d = 0; d < 4; d++)
        pk.p[d] = __float22bfloat162_rn(make_float2(h[q * 8 + 2 * d], h[q * 8 + 2 * d + 1]));
      Hw[(size_t)(f * 4 + q) * B_N + b] = pk.u;
    }
  }
}

// ---------------- GEMM: out[b][e] = sum_k Hw[b][k]*W2T[k][e] + wb2[e] ------
// 128x128 tile, BK=64, 4 waves each 64x64 via mfma_f32_16x16x32_bf16 (4x4 acc)
__global__ __launch_bounds__(256) void k_gemm(const uint4* __restrict__ Hw,
                                              const uint4* __restrict__ W2T,
                                              const float* __restrict__ wb2,
                                              float* __restrict__ out) {
  __shared__ uint4 As[8 * 128];  // [ko][m] 16B = 16KB
  __shared__ uint4 Bs[8 * 128];  // [ko][n] 16KB
  int tid = threadIdx.x;
  int wave = tid >> 6, lane = tid & 63;
  // XCD swizzle: 4 N-tiles sharing one A-tile land on the same XCD (%8 rr)
  int Fb = blockIdx.x;
  int xcd = Fb & 7, loc = Fb >> 3;
  int n_idx = loc & 3;
  int m_idx = (loc >> 2) * 8 + xcd;
  int m0 = m_idx * 128, n0 = n_idx * 128;
  int wm = (wave >> 1) * 64, wn = (wave & 1) * 64;
  int quad = lane >> 4, r16 = lane & 15;

  f32x4 acc[4][4];
  f32x4 zero = {0.f, 0.f, 0.f, 0.f};
#pragma unroll
  for (int i = 0; i < 4; i++)
#pragma unroll
    for (int j = 0; j < 4; j++) acc[i][j] = zero;

  for (int kt = 0; kt < 32; ++kt) {
    int kbase = kt * 8;
#pragma unroll
    for (int c = 0; c < 8; c++) {
      int cid = wave * 8 + c;  // 0..31, wave-uniform
      if (cid < 16) {
        int ko = cid >> 1, half = cid & 1;
        gl2lds16(Hw + (size_t)(kbase + ko) * B_N + m0 + half * 64 + lane,
                 &As[ko * 128 + half * 64]);
      } else {
        int cc = cid - 16, ko = cc >> 1, half = cc & 1;
        gl2lds16(W2T + (size_t)(kbase + ko) * E_N + n0 + half * 64 + lane,
                 &Bs[ko * 128 + half * 64]);
      }
    }
    __syncthreads();
#pragma unroll
    for (int ks = 0; ks < 2; ++ks) {
      bf16x8 af[4], bfg[4];
#pragma unroll
      for (int tm = 0; tm < 4; tm++) {
        uint4 v = As[(ks * 4 + quad) * 128 + wm + tm * 16 + r16];
        af[tm] = __builtin_bit_cast(bf16x8, v);
      }
#pragma unroll
      for (int tn = 0; tn < 4; tn++) {
        uint4 v = Bs[(ks * 4 + quad) * 128 + wn + tn * 16 + r16];
        bfg[tn] = __builtin_bit_cast(bf16x8, v);
      }
#pragma unroll
      for (int tm = 0; tm < 4; tm++)
#pragma unroll
        for (int tn = 0; tn < 4; tn++)
          acc[tm][tn] = __builtin_amdgcn_mfma_f32_16x16x32_bf16(af[tm], bfg[tn],
                                                                acc[tm][tn], 0, 0, 0);
    }
    __syncthreads();
  }
  // epilogue: C/D layout col=lane&15, row=quad*4+reg
#pragma unroll
  for (int tn = 0; tn < 4; tn++) {
    int n = n0 + wn + tn * 16 + r16;
    float bias = wb2[n];
#pragma unroll
    for (int tm = 0; tm < 4; tm++) {
#pragma unroll
      for (int rr = 0; rr < 4; rr++) {
        int m = m0 + wm + tm * 16 + quad * 4 + rr;
        out[(size_t)m * E_N + n] = acc[tm][tn][rr] + bias;
      }
    }
  }
}

// ---------------- correctness fallback if ws_size too small ----------------
__global__ __launch_bounds__(64) void k_naive(const float* __restrict__ bf,
                                              const float* __restrict__ w_raw,
                                              const float* __restrict__ W1,
                                              const float* __restrict__ b1,
                                              const float* __restrict__ gamma,
                                              const float* __restrict__ beta,
                                              const float* __restrict__ W2,
                                              const float* __restrict__ b2,
                                              float* __restrict__ out) {
  int b = blockIdx.x;
  int lane = threadIdx.x;
  float m = -1e30f;
  for (int i = 0; i < F_N; i++) m = fmaxf(m, w_raw[i]);
  float s = 0.f;
  for (int i = 0; i < F_N; i++) s += expf(w_raw[i] - m);
  float inv_s = 1.0f / s;
  float acc[8];
#pragma unroll
  for (int r = 0; r < 8; r++) acc[r] = 0.f;
  __shared__ float hs[32];
  for (int f = 0; f < F_N; f++) {
    float wf = expf(w_raw[f] - m) * inv_s;
    __syncthreads();
    if (lane < 32) {
      float x = bf[(size_t)b * F_N + f];
      float t = x * 0.015915494309189535f;
      float h = b1[f * 32 + lane];
#pragma unroll
      for (int i = 0; i < 16; i++) {
        float y = t - floorf(t);
        h = fmaf(__builtin_amdgcn_sinf(y), W1[f * 1024 + i * 32 + lane], h);
        h = fmaf(__builtin_amdgcn_cosf(y), W1[f * 1024 + 512 + i * 32 + lane], h);
        t = t + t;
      }
      float sum = h;
#pragma unroll
      for (int msk = 1; msk < 32; msk <<= 1) sum += __shfl_xor(sum, msk, 64);
      float mu = sum * (1.0f / 32.0f);
      float d = h - mu;
      float sq = d * d;
#pragma unroll
      for (int msk = 1; msk < 32; msk <<= 1) sq += __shfl_xor(sq, msk, 64);
      float rs = __builtin_amdgcn_rsqf(fmaf(sq, (1.0f / 32.0f), 1e-5f));
      float hn = fmaf(d * rs, gamma[f * 32 + lane], beta[f * 32 + lane]);
      hs[lane] = gelu_exact(hn) * wf;
    }
    __syncthreads();
#pragma unroll
    for (int r = 0; r < 8; r++) {
      int e = r * 64 + lane;
      float a = fmaf(wf, b2[f * E_N + e], acc[r]);
      for (int j = 0; j < 32; j++)
        a = fmaf(hs[j], W2[(size_t)(f * 32 + j) * E_N + e], a);
      acc[r] = a;
    }
  }
#pragma unroll
  for (int r = 0; r < 8; r++) out[(size_t)b * E_N + r * 64 + lane] = acc[r];
  if (b == 0) out[(size_t)B_N * E_N + lane] = expf(w_raw[lane] - m) * inv_s;
}

extern "C" void kernel_launch(void* const* d_in, const int* in_sizes, int n_in,
                              void* d_out, int out_size, void* d_ws, size_t ws_size,
                              hipStream_t stream) {
  const float* bf    = (const float*)d_in[0];
  const float* w_raw = (const float*)d_in[1];
  const float* W1    = (const float*)d_in[2];
  const float* b1    = (const float*)d_in[3];
  const float* gamma = (const float*)d_in[4];
  const float* beta  = (const float*)d_in[5];
  const float* W2    = (const float*)d_in[6];
  const float* b2    = (const float*)d_in[7];
  float* out = (float*)d_out;

  const size_t HW_BYTES  = (size_t)256 * B_N * 16;  // 256 MB bf16 blocked Hw
  const size_t W2T_OFF   = HW_BYTES;
  const size_t W2T_BYTES = (size_t)256 * E_N * 16;  // 2 MB
  const size_t W_OFF     = W2T_OFF + W2T_BYTES;
  const size_t WB2_OFF   = W_OFF + 256;
  const size_t NEED      = WB2_OFF + 4096;

  if (ws_size < NEED) {  // deterministic fallback (correctness insurance)
    k_naive<<<B_N, 64, 0, stream>>>(bf, w_raw, W1, b1, gamma, beta, W2, b2, out);
    return;
  }
  char* ws = (char*)d_ws;
  uint4* Hw  = (uint4*)ws;
  uint4* W2T = (uint4*)(ws + W2T_OFF);
  float* w_s = (float*)(ws + W_OFF);
  float* wb2 = (float*)(ws + WB2_OFF);

  k_prep<<<1, 256, 0, stream>>>(w_raw, b2, w_s, wb2, out + (size_t)B_N * E_N);
  k_w2t<<<256, 256, 0, stream>>>(W2, W2T);
  k_hw<<<1024, 256, 0, stream>>>(bf, W1, b1, gamma, beta, w_s, Hw);
  k_gemm<<<2048, 256, 0, stream>>>(Hw, W2T, wb2, out);
}

// Round 2
// 497.649 us; speedup vs baseline: 1.5973x; 1.5973x over previous
//
#include <hip/hip_runtime.h>
#include <hip/hip_bf16.h>
#include <cstdint>

#define B_N 65536
#define F_N 64
#define L_N 32
#define E_N 512
// K = F*L = 2048, k-octs = 256

typedef short bf16x8 __attribute__((ext_vector_type(8)));
typedef float f32x4 __attribute__((ext_vector_type(4)));

typedef __attribute__((address_space(1))) const unsigned int gas_u32;
typedef __attribute__((address_space(3))) unsigned int las_u32;

__device__ __forceinline__ void gl2lds16(const void* g, void* l) {
  __builtin_amdgcn_global_load_lds((gas_u32*)g, (las_u32*)l, 16, 0, 0);
}

// exact GELU via Abramowitz-Stegun 7.1.26 erf (|abs err| <= 1.5e-7)
__device__ __forceinline__ float gelu_exact(float v) {
  float z  = v * 0.7071067811865476f;
  float az = fabsf(z);
  float t  = __builtin_amdgcn_rcpf(fmaf(0.3275911f, az, 1.0f));
  float p  = t * fmaf(t, fmaf(t, fmaf(t, fmaf(t, 1.061405429f, -1.453152027f),
                                      1.421413741f), -0.284496736f), 0.254829592f);
  float e    = __expf(-z * z);
  float erfa = fmaf(-p, e, 1.0f);
  float er   = (z < 0.0f) ? -erfa : erfa;
  return v * fmaf(0.5f, er, 0.5f);
}

// ---------------- prep: softmax(w_raw), wb2 = w @ b2, w -> d_out tail ------
// 4 blocks x 128 threads; softmax recomputed redundantly per block (64-elem)
__global__ __launch_bounds__(128) void k_prep(const float* __restrict__ w_raw,
                                              const float* __restrict__ b2,
                                              float* __restrict__ w_s,
                                              float* __restrict__ wb2,
                                              float* __restrict__ out_tail) {
  int tid = threadIdx.x;
  float m = -1e30f;
  for (int i = 0; i < F_N; i++) m = fmaxf(m, w_raw[i]);
  float s = 0.f;
  for (int i = 0; i < F_N; i++) s += expf(w_raw[i] - m);
  float inv_s = 1.0f / s;
  if (blockIdx.x == 0 && tid < F_N) {
    float wv = expf(w_raw[tid] - m) * inv_s;
    w_s[tid] = wv;
    out_tail[tid] = wv;
  }
  int e = blockIdx.x * 128 + tid;
  float a = 0.f;
  for (int f = 0; f < F_N; f++)
    a = fmaf(expf(w_raw[f] - m) * inv_s, b2[f * E_N + e], a);
  wb2[e] = a;
}

// ---------------- W1 -> bf16 MFMA-A-fragment table ------------------------
// W1T[(f*2+jt)*64 + lane] = 8 bf16 { W1[f][quad*8+jj][jt*16+r16], jj=0..7 }
__global__ __launch_bounds__(64) void k_w1t(const float* __restrict__ W1,
                                            uint4* __restrict__ W1T) {
  int f = blockIdx.x;
  int lane = threadIdx.x;
  int quad = lane >> 4, r16 = lane & 15;
#pragma unroll
  for (int jt = 0; jt < 2; jt++) {
    union { __hip_bfloat162 p[4]; uint4 u; } pk;
#pragma unroll
    for (int d = 0; d < 4; d++) {
      float lo = W1[f * 1024 + (quad * 8 + 2 * d) * 32 + jt * 16 + r16];
      float hi = W1[f * 1024 + (quad * 8 + 2 * d + 1) * 32 + jt * 16 + r16];
      pk.p[d] = __float22bfloat162_rn(make_float2(lo, hi));
    }
    W1T[(f * 2 + jt) * 64 + lane] = pk.u;
  }
}

// ---------------- W2 [2048][512] fp32 -> blocked bf16 [k_oct][e][8] --------
__global__ __launch_bounds__(256) void k_w2t(const float* __restrict__ W2,
                                             uint4* __restrict__ W2T) {
  __shared__ float ls[64 * 65];
  int kt = blockIdx.x >> 3, et = blockIdx.x & 7;
  int k0 = kt * 64, e0 = et * 64;
  int tid = threadIdx.x;
#pragma unroll
  for (int i = 0; i < 16; i++) {
    int idx = i * 256 + tid;
    int r = idx >> 6, c = idx & 63;
    ls[r * 65 + c] = W2[(size_t)(k0 + r) * E_N + e0 + c];
  }
  __syncthreads();
#pragma unroll
  for (int i = 0; i < 2; i++) {
    int t = i * 256 + tid;
    int ko = t >> 6, e = t & 63;
    union { __hip_bfloat162 p[4]; uint4 u; } pk;
#pragma unroll
    for (int d = 0; d < 4; d++)
      pk.p[d] = __float22bfloat162_rn(make_float2(ls[(ko * 8 + 2 * d) * 65 + e],
                                                  ls[(ko * 8 + 2 * d + 1) * 65 + e]));
    W2T[(size_t)(kt * 8 + ko) * E_N + e0 + e] = pk.u;
  }
}

// ---------------- Hw = w[f]*gelu(LN(enc@W1+b1)), MFMA version -------------
// block: 64 b x all 64 f; wave w handles f = w*16..w*16+15
// per f: H^T = W1^T(16j x 32k) @ enc^T(32k x 16b) via 2jt x 4bt MFMAs
__global__ __launch_bounds__(256) void k_hw2(const float* __restrict__ bf,
                                             const uint4* __restrict__ W1T,
                                             const float* __restrict__ b1,
                                             const float* __restrict__ gamma,
                                             const float* __restrict__ beta,
                                             const float* __restrict__ w_s,
                                             char* __restrict__ HwB) {
  __shared__ float xs[64 * 65];
  int tid = threadIdx.x;
  int b0 = blockIdx.x * 64;
#pragma unroll
  for (int i = 0; i < 16; i++) {
    int idx = i * 256 + tid;
    xs[(idx >> 6) * 65 + (idx & 63)] = bf[(size_t)b0 * F_N + idx];
  }
  __syncthreads();
  int wave = tid >> 6, lane = tid & 63;
  int quad = lane >> 4, r16 = lane & 15;
  // enc lane constants: k = quad*8+jj ; k<16 -> sin(freq_k x), k>=16 -> cos
  // t in revolutions; cos = sin(t + 0.25 rev)
  float c_t   = 0.015915494309189535f * ((quad & 1) ? 256.0f : 1.0f);
  float phase = (quad >= 2) ? 0.25f : 0.0f;
  f32x4 zero = {0.f, 0.f, 0.f, 0.f};

  for (int it = 0; it < 16; ++it) {
    int f = wave * 16 + it;
    // A-fragments (W1^T, bf16, precomputed; L2-hot 128KB)
    bf16x8 a0 = __builtin_bit_cast(bf16x8, W1T[(f * 2 + 0) * 64 + lane]);
    bf16x8 a1 = __builtin_bit_cast(bf16x8, W1T[(f * 2 + 1) * 64 + lane]);
    // per-j constants: j = jt*16 + quad*4 + rr  (L2-hot 8KB each)
    float b1v[8], gv[8], bev[8];
#pragma unroll
    for (int jt = 0; jt < 2; jt++)
#pragma unroll
      for (int rr = 0; rr < 4; rr++) {
        int idx = f * 32 + jt * 16 + quad * 4 + rr;
        b1v[jt * 4 + rr] = b1[idx];
        gv[jt * 4 + rr]  = gamma[idx];
        bev[jt * 4 + rr] = beta[idx];
      }
    float wf = w_s[f];

    f32x4 acc[2][4];
#pragma unroll
    for (int bt = 0; bt < 4; bt++) {
      float x = xs[(bt * 16 + r16) * 65 + f];
      float v[8];
      float t = x * c_t;
#pragma unroll
      for (int jj = 0; jj < 8; jj++) {
        float y = t + phase;
        y = y - floorf(y);
        v[jj] = __builtin_amdgcn_sinf(y);
        t = t + t;
      }
      union { __hip_bfloat162 p[4]; bf16x8 r; } pk;
#pragma unroll
      for (int d = 0; d < 4; d++)
        pk.p[d] = __float22bfloat162_rn(make_float2(v[2 * d], v[2 * d + 1]));
      acc[0][bt] = __builtin_amdgcn_mfma_f32_16x16x32_bf16(a0, pk.r, zero, 0, 0, 0);
      acc[1][bt] = __builtin_amdgcn_mfma_f32_16x16x32_bf16(a1, pk.r, zero, 0, 0, 0);
    }

    // per-b LN over 32 j, then gamma/beta, GELU, * w[f], pack+store
#pragma unroll
    for (int bt = 0; bt < 4; bt++) {
      float h[8];
#pragma unroll
      for (int jt = 0; jt < 2; jt++)
#pragma unroll
        for (int rr = 0; rr < 4; rr++)
          h[jt * 4 + rr] = acc[jt][bt][rr] + b1v[jt * 4 + rr];
      float s = 0.f;
#pragma unroll
      for (int q = 0; q < 8; q++) s += h[q];
      s += __shfl_xor(s, 16);
      s += __shfl_xor(s, 32);
      float mu = s * (1.0f / 32.0f);
      float var = 0.f;
#pragma unroll
      for (int q = 0; q < 8; q++) { h[q] -= mu; var = fmaf(h[q], h[q], var); }
      var += __shfl_xor(var, 16);
      var += __shfl_xor(var, 32);
      float rs = __builtin_amdgcn_rsqf(fmaf(var, (1.0f / 32.0f), 1e-5f));
#pragma unroll
      for (int q = 0; q < 8; q++) {
        float hn = fmaf(h[q] * rs, gv[q], bev[q]);
        h[q] = gelu_exact(hn) * wf;
      }
      int b = b0 + bt * 16 + r16;
#pragma unroll
      for (int jt = 0; jt < 2; jt++) {
        union { __hip_bfloat162 p[2]; uint2 u; } pk;
        pk.p[0] = __float22bfloat162_rn(make_float2(h[jt * 4 + 0], h[jt * 4 + 1]));
        pk.p[1] = __float22bfloat162_rn(make_float2(h[jt * 4 + 2], h[jt * 4 + 3]));
        size_t off = ((size_t)(f * 4 + jt * 2 + (quad >> 1)) * B_N + b) * 16 +
                     (quad & 1) * 8;
        *(uint2*)(HwB + off) = pk.u;
      }
    }
  }
}

// ---------------- GEMM: out[b][e] = sum_k Hw[b][k]*W2T[k][e] + wb2[e] ------
// (unchanged from R1 for clean counter attribution)
__global__ __launch_bounds__(256) void k_gemm(const uint4* __restrict__ Hw,
                                              const uint4* __restrict__ W2T,
                                              const float* __restrict__ wb2,
                                              float* __restrict__ out) {
  __shared__ uint4 As[8 * 128];
  __shared__ uint4 Bs[8 * 128];
  int tid = threadIdx.x;
  int wave = tid >> 6, lane = tid & 63;
  int Fb = blockIdx.x;
  int xcd = Fb & 7, loc = Fb >> 3;
  int n_idx = loc & 3;
  int m_idx = (loc >> 2) * 8 + xcd;
  int m0 = m_idx * 128, n0 = n_idx * 128;
  int wm = (wave >> 1) * 64, wn = (wave & 1) * 64;
  int quad = lane >> 4, r16 = lane & 15;

  f32x4 acc[4][4];
  f32x4 zero = {0.f, 0.f, 0.f, 0.f};
#pragma unroll
  for (int i = 0; i < 4; i++)
#pragma unroll
    for (int j = 0; j < 4; j++) acc[i][j] = zero;

  for (int kt = 0; kt < 32; ++kt) {
    int kbase = kt * 8;
#pragma unroll
    for (int c = 0; c < 8; c++) {
      int cid = wave * 8 + c;
      if (cid < 16) {
        int ko = cid >> 1, half = cid & 1;
        gl2lds16(Hw + (size_t)(kbase + ko) * B_N + m0 + half * 64 + lane,
                 &As[ko * 128 + half * 64]);
      } else {
        int cc = cid - 16, ko = cc >> 1, half = cc & 1;
        gl2lds16(W2T + (size_t)(kbase + ko) * E_N + n0 + half * 64 + lane,
                 &Bs[ko * 128 + half * 64]);
      }
    }
    __syncthreads();
#pragma unroll
    for (int ks = 0; ks < 2; ++ks) {
      bf16x8 af[4], bfg[4];
#pragma unroll
      for (int tm = 0; tm < 4; tm++) {
        uint4 v = As[(ks * 4 + quad) * 128 + wm + tm * 16 + r16];
        af[tm] = __builtin_bit_cast(bf16x8, v);
      }
#pragma unroll
      for (int tn = 0; tn < 4; tn++) {
        uint4 v = Bs[(ks * 4 + quad) * 128 + wn + tn * 16 + r16];
        bfg[tn] = __builtin_bit_cast(bf16x8, v);
      }
#pragma unroll
      for (int tm = 0; tm < 4; tm++)
#pragma unroll
        for (int tn = 0; tn < 4; tn++)
          acc[tm][tn] = __builtin_amdgcn_mfma_f32_16x16x32_bf16(af[tm], bfg[tn],
                                                                acc[tm][tn], 0, 0, 0);
    }
    __syncthreads();
  }
#pragma unroll
  for (int tn = 0; tn < 4; tn++) {
    int n = n0 + wn + tn * 16 + r16;
    float bias = wb2[n];
#pragma unroll
    for (int tm = 0; tm < 4; tm++) {
#pragma unroll
      for (int rr = 0; rr < 4; rr++) {
        int m = m0 + wm + tm * 16 + quad * 4 + rr;
        out[(size_t)m * E_N + n] = acc[tm][tn][rr] + bias;
      }
    }
  }
}

// ---------------- correctness fallback if ws_size too small ----------------
__global__ __launch_bounds__(64) void k_naive(const float* __restrict__ bf,
                                              const float* __restrict__ w_raw,
                                              const float* __restrict__ W1,
                                              const float* __restrict__ b1,
                                              const float* __restrict__ gamma,
                                              const float* __restrict__ beta,
                                              const float* __restrict__ W2,
                                              const float* __restrict__ b2,
                                              float* __restrict__ out) {
  int b = blockIdx.x;
  int lane = threadIdx.x;
  float m = -1e30f;
  for (int i = 0; i < F_N; i++) m = fmaxf(m, w_raw[i]);
  float s = 0.f;
  for (int i = 0; i < F_N; i++) s += expf(w_raw[i] - m);
  float inv_s = 1.0f / s;
  float acc[8];
#pragma unroll
  for (int r = 0; r < 8; r++) acc[r] = 0.f;
  __shared__ float hs[32];
  for (int f = 0; f < F_N; f++) {
    float wf = expf(w_raw[f] - m) * inv_s;
    __syncthreads();
    if (lane < 32) {
      float x = bf[(size_t)b * F_N + f];
      float t = x * 0.015915494309189535f;
      float h = b1[f * 32 + lane];
#pragma unroll
      for (int i = 0; i < 16; i++) {
        float y = t - floorf(t);
        h = fmaf(__builtin_amdgcn_sinf(y), W1[f * 1024 + i * 32 + lane], h);
        h = fmaf(__builtin_amdgcn_cosf(y), W1[f * 1024 + 512 + i * 32 + lane], h);
        t = t + t;
      }
      float sum = h;
#pragma unroll
      for (int msk = 1; msk < 32; msk <<= 1) sum += __shfl_xor(sum, msk, 64);
      float mu = sum * (1.0f / 32.0f);
      float d = h - mu;
      float sq = d * d;
#pragma unroll
      for (int msk = 1; msk < 32; msk <<= 1) sq += __shfl_xor(sq, msk, 64);
      float rs = __builtin_amdgcn_rsqf(fmaf(sq, (1.0f / 32.0f), 1e-5f));
      float hn = fmaf(d * rs, gamma[f * 32 + lane], beta[f * 32 + lane]);
      hs[lane] = gelu_exact(hn) * wf;
    }
    __syncthreads();
#pragma unroll
    for (int r = 0; r < 8; r++) {
      int e = r * 64 + lane;
      float a = fmaf(wf, b2[f * E_N + e], acc[r]);
      for (int j = 0; j < 32; j++)
        a = fmaf(hs[j], W2[(size_t)(f * 32 + j) * E_N + e], a);
      acc[r] = a;
    }
  }
#pragma unroll
  for (int r = 0; r < 8; r++) out[(size_t)b * E_N + r * 64 + lane] = acc[r];
  if (b == 0) out[(size_t)B_N * E_N + lane] = expf(w_raw[lane] - m) * inv_s;
}

extern "C" void kernel_launch(void* const* d_in, const int* in_sizes, int n_in,
                              void* d_out, int out_size, void* d_ws, size_t ws_size,
                              hipStream_t stream) {
  const float* bf    = (const float*)d_in[0];
  const float* w_raw = (const float*)d_in[1];
  const float* W1    = (const float*)d_in[2];
  const float* b1    = (const float*)d_in[3];
  const float* gamma = (const float*)d_in[4];
  const float* beta  = (const float*)d_in[5];
  const float* W2    = (const float*)d_in[6];
  const float* b2    = (const float*)d_in[7];
  float* out = (float*)d_out;

  const size_t HW_BYTES  = (size_t)256 * B_N * 16;  // 256 MB bf16 blocked Hw
  const size_t W2T_OFF   = HW_BYTES;
  const size_t W2T_BYTES = (size_t)256 * E_N * 16;  // 2 MB
  const size_t W_OFF     = W2T_OFF + W2T_BYTES;
  const size_t WB2_OFF   = W_OFF + 256;
  const size_t W1T_OFF   = WB2_OFF + 4096;
  const size_t NEED      = W1T_OFF + 131072;

  if (ws_size < NEED) {  // deterministic fallback (correctness insurance)
    k_naive<<<B_N, 64, 0, stream>>>(bf, w_raw, W1, b1, gamma, beta, W2, b2, out);
    return;
  }
  char* ws = (char*)d_ws;
  uint4* Hw  = (uint4*)ws;
  uint4* W2T = (uint4*)(ws + W2T_OFF);
  float* w_s = (float*)(ws + W_OFF);
  float* wb2 = (float*)(ws + WB2_OFF);
  uint4* W1T = (uint4*)(ws + W1T_OFF);

  k_prep<<<4, 128, 0, stream>>>(w_raw, b2, w_s, wb2, out + (size_t)B_N * E_N);
  k_w1t<<<64, 64, 0, stream>>>(W1, W1T);
  k_w2t<<<256, 256, 0, stream>>>(W2, W2T);
  k_hw2<<<1024, 256, 0, stream>>>(bf, W1T, b1, gamma, beta, w_s, (char*)Hw);
  k_gemm<<<2048, 256, 0, stream>>>(Hw, W2T, wb2, out);
}